// Round 1
// baseline (5915.351 us; speedup 1.0000x reference)
//
#include <hip/hip_runtime.h>
#include <math.h>

// ---- geometry constants (match reference) ----
#define NA   24
#define NU   128
#define NV   64
#define NW   128   // volume W (x)
#define NH   128   // volume H (y)
#define ND   64    // volume D (z)
#define NS   128   // samples per ray
#define F_SID 256.0f
#define F_SDD 512.0f
#define F_STEP 1.5625f            // 2*HS/S = 200/128
#define F_DL  (200.0f / 127.0f)   // linspace(156,356,128) spacing
#define F_L0  156.0f

#define NRAYS (NA * NV * NU)      // 196608

// Per-ray geometry: returns source xy, unit dir. Angle computed like
// np.deg2rad(linspace(0,360,24,False)).astype(f32).
__device__ __forceinline__ void ray_setup(int a, int v, int u,
                                          float& sx, float& sy,
                                          float& dx, float& dy, float& dz) {
    float ang = (float)((double)a * (15.0 * M_PI / 180.0));
    float c = cosf(ang), s = sinf(ang);
    float uu = (float)u - 63.5f;
    float vv = (float)v - 31.5f;
    float ux = F_SDD * c - uu * s;   // pix - src, x
    float uy = F_SDD * s + uu * c;   // pix - src, y
    float uz = vv;
    float invn = 1.0f / sqrtf(ux * ux + uy * uy + uz * uz);
    dx = ux * invn; dy = uy * invn; dz = uz * invn;
    sx = -F_SID * c; sy = -F_SID * s;
}

// ---------------- forward projection + residual + cosine weight ----------------
__global__ __launch_bounds__(256) void fp_res_kernel(const float* __restrict__ vol,
                                                     const float* __restrict__ p,
                                                     float* __restrict__ res) {
    int r = blockIdx.x * blockDim.x + threadIdx.x;
    if (r >= NRAYS) return;
    int u = r & (NU - 1);
    int v = (r >> 7) & (NV - 1);
    int a = r >> 13;

    float sx, sy, dx, dy, dz;
    ray_setup(a, v, u, sx, sy, dx, dy, dz);

    float acc = 0.0f;
#pragma unroll 4
    for (int i = 0; i < NS; ++i) {
        float ell = F_L0 + F_DL * (float)i;
        float cx = sx + ell * dx + 63.5f;   // -> W index
        float cy = sy + ell * dy + 63.5f;   // -> H index
        float cz =      ell * dz + 31.5f;   // -> D index
        float fx = floorf(cx), fy = floorf(cy), fz = floorf(cz);
        int ix = (int)fx, iy = (int)fy, iz = (int)fz;
        float wx1 = cx - fx, wy1 = cy - fy, wz1 = cz - fz;
        float wx0 = 1.0f - wx1, wy0 = 1.0f - wy1, wz0 = 1.0f - wz1;
        bool bx0 = (unsigned)ix < NW,      bx1 = (unsigned)(ix + 1) < NW;
        bool by0 = (unsigned)iy < NH,      by1 = (unsigned)(iy + 1) < NH;
        bool bz0 = (unsigned)iz < ND,      bz1 = (unsigned)(iz + 1) < ND;
        long base = ((long)iz * NH + iy) * NW + ix;
        float v000 = (bz0 && by0 && bx0) ? vol[base]                 : 0.0f;
        float v001 = (bz0 && by0 && bx1) ? vol[base + 1]             : 0.0f;
        float v010 = (bz0 && by1 && bx0) ? vol[base + NW]            : 0.0f;
        float v011 = (bz0 && by1 && bx1) ? vol[base + NW + 1]        : 0.0f;
        float v100 = (bz1 && by0 && bx0) ? vol[base + NH * NW]       : 0.0f;
        float v101 = (bz1 && by0 && bx1) ? vol[base + NH * NW + 1]   : 0.0f;
        float v110 = (bz1 && by1 && bx0) ? vol[base + NH * NW + NW]  : 0.0f;
        float v111 = (bz1 && by1 && bx1) ? vol[base + NH * NW + NW + 1] : 0.0f;
        acc += wz0 * (wy0 * (wx0 * v000 + wx1 * v001) +
                      wy1 * (wx0 * v010 + wx1 * v011)) +
               wz1 * (wy0 * (wx0 * v100 + wx1 * v101) +
                      wy1 * (wx0 * v110 + wx1 * v111));
    }
    float sino = acc * F_STEP;
    // cosine weight: note (v - V/2), (u - U/2) — NOT the ray's half-pixel offsets.
    double du = (double)u - 64.0;
    double dv = (double)v - 32.0;
    float cw = (float)(512.0 / sqrt(512.0 * 512.0 + dv * dv + du * du));
    res[r] = (sino - p[r]) * cw;
}

// ---------------- Ram-Lak ramp filter along u (in place) ----------------
// out[u] = 0.125*in[u] + sum_{odd d=1..63} (-0.5/(pi^2 d^2)) * (in[u-d] + in[u+d])
__global__ __launch_bounds__(NU) void ramp_kernel(float* __restrict__ res) {
    __shared__ float row[NU];
    int rowid = blockIdx.x;          // a*NV + v
    int u = threadIdx.x;             // 0..127
    row[u] = res[rowid * NU + u];
    __syncthreads();
    float acc = 0.125f * row[u];
#pragma unroll
    for (int d = 1; d <= 63; d += 2) {
        float f = (float)(-0.5 / (M_PI * M_PI * (double)(d * d)));
        float lo = (u - d >= 0) ? row[u - d] : 0.0f;
        float hi = (u + d < NU) ? row[u + d] : 0.0f;
        acc += f * (lo + hi);
    }
    res[rowid * NU + u] = acc;
}

// ---------------- back projection: exact adjoint scatter ----------------
__global__ __launch_bounds__(256) void bp_kernel(const float* __restrict__ res,
                                                 float* __restrict__ out) {
    int r = blockIdx.x * blockDim.x + threadIdx.x;
    if (r >= NRAYS) return;
    int u = r & (NU - 1);
    int v = (r >> 7) & (NV - 1);
    int a = r >> 13;

    float sx, sy, dx, dy, dz;
    ray_setup(a, v, u, sx, sy, dx, dy, dz);

    float val = res[r] * F_STEP;   // LAMB = 1
    for (int i = 0; i < NS; ++i) {
        float ell = F_L0 + F_DL * (float)i;
        float cx = sx + ell * dx + 63.5f;
        float cy = sy + ell * dy + 63.5f;
        float cz =      ell * dz + 31.5f;
        float fx = floorf(cx), fy = floorf(cy), fz = floorf(cz);
        int ix = (int)fx, iy = (int)fy, iz = (int)fz;
        float wx1 = cx - fx, wy1 = cy - fy, wz1 = cz - fz;
        float wx0 = 1.0f - wx1, wy0 = 1.0f - wy1, wz0 = 1.0f - wz1;
        bool bx0 = (unsigned)ix < NW,      bx1 = (unsigned)(ix + 1) < NW;
        bool by0 = (unsigned)iy < NH,      by1 = (unsigned)(iy + 1) < NH;
        bool bz0 = (unsigned)iz < ND,      bz1 = (unsigned)(iz + 1) < ND;
        long base = ((long)iz * NH + iy) * NW + ix;
        if (bz0 && by0 && bx0) atomicAdd(&out[base],                wz0 * wy0 * wx0 * val);
        if (bz0 && by0 && bx1) atomicAdd(&out[base + 1],            wz0 * wy0 * wx1 * val);
        if (bz0 && by1 && bx0) atomicAdd(&out[base + NW],           wz0 * wy1 * wx0 * val);
        if (bz0 && by1 && bx1) atomicAdd(&out[base + NW + 1],       wz0 * wy1 * wx1 * val);
        if (bz1 && by0 && bx0) atomicAdd(&out[base + NH * NW],      wz1 * wy0 * wx0 * val);
        if (bz1 && by0 && bx1) atomicAdd(&out[base + NH * NW + 1],  wz1 * wy0 * wx1 * val);
        if (bz1 && by1 && bx0) atomicAdd(&out[base + NH * NW + NW], wz1 * wy1 * wx0 * val);
        if (bz1 && by1 && bx1) atomicAdd(&out[base + NH * NW + NW + 1], wz1 * wy1 * wx1 * val);
    }
}

extern "C" void kernel_launch(void* const* d_in, const int* in_sizes, int n_in,
                              void* d_out, int out_size, void* d_ws, size_t ws_size,
                              hipStream_t stream) {
    const float* x = (const float*)d_in[0];   // [1,1,64,128,128]
    const float* p = (const float*)d_in[1];   // [1,1,24,64,128]
    float* out = (float*)d_out;               // [1,1,64,128,128]
    float* res = (float*)d_ws;                // NRAYS floats (786 KB)

    // d_out is poisoned 0xAA before every launch — zero it for the atomic scatter.
    hipMemsetAsync(out, 0, (size_t)out_size * sizeof(float), stream);

    fp_res_kernel<<<NRAYS / 256, 256, 0, stream>>>(x, p, res);
    ramp_kernel<<<NA * NV, NU, 0, stream>>>(res);
    bp_kernel<<<NRAYS / 256, 256, 0, stream>>>(res, out);
}

// Round 2
// 836.580 us; speedup vs baseline: 7.0709x; 7.0709x over previous
//
#include <hip/hip_runtime.h>
#include <math.h>

// ---- geometry constants (match reference) ----
#define NA   24
#define NU   128
#define NV   64
#define NW   128   // volume W (x)
#define NH   128   // volume H (y)
#define ND   64    // volume D (z)
#define NS   128   // samples per ray
#define F_SID 256.0f
#define F_SDD 512.0f
#define F_STEP 1.5625f            // 2*HS/S = 200/128
#define F_DL  (200.0f / 127.0f)   // linspace(156,356,128) spacing
#define F_L0  156.0f

#define NRAYS (NA * NV * NU)      // 196608

// Per-ray geometry: returns source xy, unit dir.
__device__ __forceinline__ void ray_setup(int a, int v, int u,
                                          float& sx, float& sy,
                                          float& dx, float& dy, float& dz) {
    float ang = (float)((double)a * (15.0 * M_PI / 180.0));
    float c = cosf(ang), s = sinf(ang);
    float uu = (float)u - 63.5f;
    float vv = (float)v - 31.5f;
    float ux = F_SDD * c - uu * s;   // pix - src, x
    float uy = F_SDD * s + uu * c;   // pix - src, y
    float uz = vv;
    float invn = 1.0f / sqrtf(ux * ux + uy * uy + uz * uz);
    dx = ux * invn; dy = uy * invn; dz = uz * invn;
    sx = -F_SID * c; sy = -F_SID * s;
}

// ---------------- forward projection + residual + cosine weight ----------------
__global__ __launch_bounds__(256) void fp_res_kernel(const float* __restrict__ vol,
                                                     const float* __restrict__ p,
                                                     float* __restrict__ res) {
    int r = blockIdx.x * blockDim.x + threadIdx.x;
    if (r >= NRAYS) return;
    int u = r & (NU - 1);
    int v = (r >> 7) & (NV - 1);
    int a = r >> 13;

    float sx, sy, dx, dy, dz;
    ray_setup(a, v, u, sx, sy, dx, dy, dz);

    float acc = 0.0f;
#pragma unroll 4
    for (int i = 0; i < NS; ++i) {
        float ell = F_L0 + F_DL * (float)i;
        float cx = sx + ell * dx + 63.5f;   // -> W index
        float cy = sy + ell * dy + 63.5f;   // -> H index
        float cz =      ell * dz + 31.5f;   // -> D index
        float fx = floorf(cx), fy = floorf(cy), fz = floorf(cz);
        int ix = (int)fx, iy = (int)fy, iz = (int)fz;
        float wx1 = cx - fx, wy1 = cy - fy, wz1 = cz - fz;
        float wx0 = 1.0f - wx1, wy0 = 1.0f - wy1, wz0 = 1.0f - wz1;
        bool bx0 = (unsigned)ix < NW,      bx1 = (unsigned)(ix + 1) < NW;
        bool by0 = (unsigned)iy < NH,      by1 = (unsigned)(iy + 1) < NH;
        bool bz0 = (unsigned)iz < ND,      bz1 = (unsigned)(iz + 1) < ND;
        long base = ((long)iz * NH + iy) * NW + ix;
        float v000 = (bz0 && by0 && bx0) ? vol[base]                 : 0.0f;
        float v001 = (bz0 && by0 && bx1) ? vol[base + 1]             : 0.0f;
        float v010 = (bz0 && by1 && bx0) ? vol[base + NW]            : 0.0f;
        float v011 = (bz0 && by1 && bx1) ? vol[base + NW + 1]        : 0.0f;
        float v100 = (bz1 && by0 && bx0) ? vol[base + NH * NW]       : 0.0f;
        float v101 = (bz1 && by0 && bx1) ? vol[base + NH * NW + 1]   : 0.0f;
        float v110 = (bz1 && by1 && bx0) ? vol[base + NH * NW + NW]  : 0.0f;
        float v111 = (bz1 && by1 && bx1) ? vol[base + NH * NW + NW + 1] : 0.0f;
        acc += wz0 * (wy0 * (wx0 * v000 + wx1 * v001) +
                      wy1 * (wx0 * v010 + wx1 * v011)) +
               wz1 * (wy0 * (wx0 * v100 + wx1 * v101) +
                      wy1 * (wx0 * v110 + wx1 * v111));
    }
    float sino = acc * F_STEP;
    double du = (double)u - 64.0;
    double dv = (double)v - 32.0;
    float cw = (float)(512.0 / sqrt(512.0 * 512.0 + dv * dv + du * du));
    res[r] = (sino - p[r]) * cw;
}

// ---------------- Ram-Lak ramp filter along u (in place) ----------------
__global__ __launch_bounds__(NU) void ramp_kernel(float* __restrict__ res) {
    __shared__ float row[NU];
    int rowid = blockIdx.x;          // a*NV + v
    int u = threadIdx.x;             // 0..127
    row[u] = res[rowid * NU + u];
    __syncthreads();
    float acc = 0.125f * row[u];
#pragma unroll
    for (int d = 1; d <= 63; d += 2) {
        float f = (float)(-0.5 / (M_PI * M_PI * (double)(d * d)));
        float lo = (u - d >= 0) ? row[u - d] : 0.0f;
        float hi = (u + d < NU) ? row[u + d] : 0.0f;
        acc += f * (lo + hi);
    }
    res[rowid * NU + u] = acc;
}

// ---------------- back projection: voxel-driven exact-adjoint GATHER ----------------
// out[X] = STEP * sum over samples with |P(a,u,v,i) - X|_inf < 1 of
//          prod(1-|delta|) * res[a,v,u].   No atomics; one store per voxel.
__global__ __launch_bounds__(256) void bp_gather_kernel(const float* __restrict__ res,
                                                        float* __restrict__ out) {
    __shared__ float s_invn[NV * NU];   // 32 KB: 1/||dir_unnorm|| per (v,u)
    __shared__ float s_cs[NA * 2];      // cos/sin per angle
    for (int t = threadIdx.x; t < NV * NU; t += blockDim.x) {
        int u = t & (NU - 1);
        int v = t >> 7;
        float uu = (float)u - 63.5f;
        float vv = (float)v - 31.5f;
        s_invn[t] = 1.0f / sqrtf(F_SDD * F_SDD + uu * uu + vv * vv);
    }
    if (threadIdx.x < NA) {
        float ang = (float)((double)threadIdx.x * (15.0 * M_PI / 180.0));
        s_cs[threadIdx.x * 2]     = cosf(ang);
        s_cs[threadIdx.x * 2 + 1] = sinf(ang);
    }
    __syncthreads();

    int id = blockIdx.x * blockDim.x + threadIdx.x;   // ((z*NH)+y)*NW + x
    int x = id & (NW - 1);
    int y = (id >> 7) & (NH - 1);
    int z = id >> 14;
    float x0 = (float)x - 63.5f;
    float y0 = (float)y - 63.5f;
    float z0 = (float)z - 31.5f;

    float acc = 0.0f;
    for (int a = 0; a < NA; ++a) {
        float c  = s_cs[a * 2];
        float sn = s_cs[a * 2 + 1];
        float Vx = x0 + F_SID * c;     // voxel - source
        float Vy = y0 + F_SID * sn;
        float ellc = sqrtf(Vx * Vx + Vy * Vy + z0 * z0);   // source->voxel distance

        // i window: |ell - ellc| < sqrt(3) (reverse triangle ineq) + margin
        float t_lo = (ellc - F_L0 - 1.785f) * (1.0f / F_DL);
        float t_hi = (ellc - F_L0 + 1.785f) * (1.0f / F_DL);
        int i_lo = max(0, (int)ceilf(t_lo));
        int i_hi = min(NS - 1, (int)floorf(t_hi));
        if (i_lo > i_hi) continue;
        float ell_lo = F_L0 + F_DL * (float)i_lo;
        float ell_hi = F_L0 + F_DL * (float)i_hi;
        // tau = ell/n, n in [512, 517.1] -> reciprocal bounds
        float inv_tmax = 512.0f / ell_hi;
        float inv_tmin = 517.1f / ell_lo;

        // u window: uu*tau in y' +- sqrt(2) (x-y box rotates; |c|+|s| <= sqrt2)
        float yp = y0 * c - x0 * sn;
        float Au = yp - 1.4143f, Bu = yp + 1.4143f;
        float ulo_f = Au * ((Au >= 0.0f) ? inv_tmax : inv_tmin);
        float uhi_f = Bu * ((Bu >= 0.0f) ? inv_tmin : inv_tmax);
        int u_lo = max(0, (int)ceilf(ulo_f + 63.5f - 0.01f));
        int u_hi = min(NU - 1, (int)floorf(uhi_f + 63.5f + 0.01f));
        if (u_lo > u_hi) continue;

        // v window: vv*tau in z0 +- 1 (z axis unrotated)
        float Av = z0 - 1.01f, Bv = z0 + 1.01f;
        float vlo_f = Av * ((Av >= 0.0f) ? inv_tmax : inv_tmin);
        float vhi_f = Bv * ((Bv >= 0.0f) ? inv_tmin : inv_tmax);
        int v_lo = max(0, (int)ceilf(vlo_f + 31.5f - 0.01f));
        int v_hi = min(NV - 1, (int)floorf(vhi_f + 31.5f + 0.01f));
        if (v_lo > v_hi) continue;

        float c512 = F_SDD * c;
        float s512 = F_SDD * sn;
        const float* resa = res + a * (NV * NU);

        for (int v = v_lo; v <= v_hi; ++v) {
            float vv = (float)v - 31.5f;
            const float* resrow = resa + v * NU;
            const float* tabrow = s_invn + v * NU;
            for (int u = u_lo; u <= u_hi; ++u) {
                float uu = (float)u - 63.5f;
                float invn = tabrow[u];
                float dx = (c512 - uu * sn) * invn;
                float dy = (s512 + uu * c)  * invn;
                float dz = vv * invn;
                float rv = resrow[u];
                float wsum = 0.0f;
                for (int i = i_lo; i <= i_hi; ++i) {
                    float ell = F_L0 + F_DL * (float)i;
                    float wx = 1.0f - fabsf(fmaf(ell, dx, -Vx));
                    float wy = 1.0f - fabsf(fmaf(ell, dy, -Vy));
                    float wz = 1.0f - fabsf(fmaf(ell, dz, -z0));
                    float m = fminf(wx, fminf(wy, wz));
                    if (m > 0.0f) wsum += wx * wy * wz;
                }
                acc = fmaf(wsum, rv, acc);
            }
        }
    }
    out[id] = acc * F_STEP;   // LAMB = 1
}

extern "C" void kernel_launch(void* const* d_in, const int* in_sizes, int n_in,
                              void* d_out, int out_size, void* d_ws, size_t ws_size,
                              hipStream_t stream) {
    const float* x = (const float*)d_in[0];   // [1,1,64,128,128]
    const float* p = (const float*)d_in[1];   // [1,1,24,64,128]
    float* out = (float*)d_out;               // [1,1,64,128,128]
    float* res = (float*)d_ws;                // NRAYS floats (786 KB)

    fp_res_kernel<<<NRAYS / 256, 256, 0, stream>>>(x, p, res);
    ramp_kernel<<<NA * NV, NU, 0, stream>>>(res);
    bp_gather_kernel<<<(NW * NH * ND) / 256, 256, 0, stream>>>(res, out);
}